// Round 14
// baseline (579.038 us; speedup 1.0000x reference)
//
#include <hip/hip_runtime.h>
#include <hip/hip_bf16.h>
#include <cstdio>

typedef unsigned short u16;
typedef __bf16 bf16x8 __attribute__((ext_vector_type(8)));
typedef float  floatx4 __attribute__((ext_vector_type(4)));

// ---------- scalar helpers ----------
__device__ __forceinline__ float bf2f(u16 u) {
  union { unsigned int i; float f; } v; v.i = ((unsigned int)u) << 16; return v.f;
}
__device__ __forceinline__ u16 f2bf(float f) {
  union { float f; unsigned int i; } v; v.f = f;
  unsigned int x = v.i;
  return (u16)((x + 0x7fffu + ((x >> 16) & 1u)) >> 16);   // RNE
}
__device__ __forceinline__ unsigned int f2bf_pk(float a, float b) {   // [lo=a, hi=b]
  __hip_bfloat162 h = __float22bfloat162_rn(make_float2(a, b));
  union { __hip_bfloat162 h; unsigned int u; } v; v.h = h; return v.u;
}
// fast gates: v_rcp (~1 ulp) + native exp — no IEEE div
__device__ __forceinline__ float sigmoidf_(float x) {
  return __builtin_amdgcn_rcpf(1.f + __expf(-x));
}
__device__ __forceinline__ float tanhf_(float x) {
  return fmaf(-2.f, __builtin_amdgcn_rcpf(1.f + __expf(2.f * x)), 1.f);
}

// LDS swizzle, 128-elem rows, 16B chunks: chunk' = chunk ^ (row&15)
__device__ __forceinline__ int swz128(int row, int c16) {
  return row * 128 + ((c16 ^ (row & 15)) << 3);
}
// element-level access into swizzled rows
__device__ __forceinline__ int swze(int row, int col) {
  return row * 128 + (((((col >> 3)) ^ (row & 15)) << 3) | (col & 7));
}

// ============ proj_e: Ep[v][col][4] = {i,u,o,f} pre-acts + biases, + fused leaf h/c ============
__global__ __launch_bounds__(256, 2) void proj_e(
    const float* __restrict__ emb, const u16* __restrict__ WT,
    const float* __restrict__ bsum, u16* __restrict__ Ep,
    u16* __restrict__ Hl, u16* __restrict__ Cl)
{
  __shared__ __align__(16) u16 ldsA[128 * 128];
  const int tid = threadIdx.x;
  const long m0 = (long)blockIdx.x * 128;
  {
    const int r = tid >> 1, half = tid & 1;
    long row = m0 + r; if (row > 49999) row = 49999;
    const float* src = emb + row * 128 + half * 64;
#pragma unroll
    for (int i = 0; i < 8; i++) {
      float4 v0 = *reinterpret_cast<const float4*>(src + i * 8);
      float4 v1 = *reinterpret_cast<const float4*>(src + i * 8 + 4);
      unsigned int ov[4] = { f2bf_pk(v0.x, v0.y), f2bf_pk(v0.z, v0.w),
                             f2bf_pk(v1.x, v1.y), f2bf_pk(v1.z, v1.w) };
      *reinterpret_cast<uint4*>(&ldsA[swz128(r, half * 8 + i)]) =
          *reinterpret_cast<const uint4*>(ov);
    }
  }
  __syncthreads();
  const int lane = tid & 63, w = tid >> 6, l16 = lane & 15, quad = lane >> 4;
#pragma unroll
  for (int half = 0; half < 2; half++) {
    const int col = w * 32 + half * 16 + l16;
    bf16x8 bI[4], bU[4], bO[4], bF[4];
#pragma unroll
    for (int ks = 0; ks < 4; ks++) {
      const size_t o_ = ks * 32 + quad * 8;
      bI[ks] = *reinterpret_cast<const bf16x8*>(WT + (size_t)(0   + col) * 128 + o_);
      bU[ks] = *reinterpret_cast<const bf16x8*>(WT + (size_t)(128 + col) * 128 + o_);
      bO[ks] = *reinterpret_cast<const bf16x8*>(WT + (size_t)(256 + col) * 128 + o_);
      bF[ks] = *reinterpret_cast<const bf16x8*>(WT + (size_t)(384 + col) * 128 + o_);
    }
    const float bi = bsum[col], bu = bsum[128 + col], bo = bsum[256 + col], bf = bsum[384 + col];
#pragma unroll
    for (int i = 0; i < 8; i++) {
      floatx4 aI = {0.f,0.f,0.f,0.f}, aU = {0.f,0.f,0.f,0.f};
      floatx4 aO = {0.f,0.f,0.f,0.f}, aF = {0.f,0.f,0.f,0.f};
#pragma unroll
      for (int ks = 0; ks < 4; ks++) {
        bf16x8 a = *reinterpret_cast<const bf16x8*>(&ldsA[swz128(i * 16 + l16, ks * 4 + quad)]);
        aI = __builtin_amdgcn_mfma_f32_16x16x32_bf16(a, bI[ks], aI, 0, 0, 0);
        aU = __builtin_amdgcn_mfma_f32_16x16x32_bf16(a, bU[ks], aU, 0, 0, 0);
        aO = __builtin_amdgcn_mfma_f32_16x16x32_bf16(a, bO[ks], aO, 0, 0, 0);
        aF = __builtin_amdgcn_mfma_f32_16x16x32_bf16(a, bF[ks], aF, 0, 0, 0);
      }
#pragma unroll
      for (int r2 = 0; r2 < 4; r2++) {
        const long row = m0 + i * 16 + quad * 4 + r2;
        if (row < 50000) {
          u16 ov[4] = { f2bf(aI[r2] + bi), f2bf(aU[r2] + bu),
                        f2bf(aO[r2] + bo), f2bf(aF[r2] + bf) };
          *reinterpret_cast<ushort4*>(Ep + row * 512 + col * 4) =
              *reinterpret_cast<const ushort4*>(ov);
          // fused leaf activations from the stored bf16 values
          const float cv = sigmoidf_(bf2f(ov[0])) * tanhf_(bf2f(ov[1]));
          const float hv = sigmoidf_(bf2f(ov[2])) * tanhf_(cv);
          Cl[row * 128 + col] = f2bf(cv);
          Hl[row * 128 + col] = f2bf(hv);
        }
      }
    }
  }
}

// ============ k_tree: one block computes one full subtree L4->L3->L2->L1->L0 ============
// Subtree of L0 node b: leaves/L4 64b..64b+63, L3 32b.., L2 16b.., L1 4b.., L0 b.
// All intermediate h/c live in LDS; HBM writes = root h only (1 MB total).
// Buffers: bufH0 (64r), bufH1 (64r) ping-pong h; cbuf (64r) holds current c level
// (parent c deferred in registers + barrier to avoid child-read/parent-write races).
// Rounding chain identical to the split-kernel version (f2bf at every boundary).
__global__ __launch_bounds__(256, 2) void k_tree(
    const int* __restrict__ sen, const u16* __restrict__ Ep,
    const u16* __restrict__ Hl, const u16* __restrict__ Cl,
    const u16* __restrict__ BfT, const u16* __restrict__ BihT,
    const u16* __restrict__ BuhT, const u16* __restrict__ BohT,
    u16* __restrict__ h_root,
    long o0, long o1, long o2, long o3, long o4, long o5)
{
  __shared__ __align__(16) u16 bufH0[64 * 128];   // 16 KB
  __shared__ __align__(16) u16 bufH1[64 * 128];   // 16 KB
  __shared__ __align__(16) u16 cbuf [64 * 128];   // 16 KB
  __shared__ int sidL4[64], sidL3[32], sidL2[16], sidL1[4], sidL0v[1];

  const int tid = threadIdx.x;
  const long b  = blockIdx.x;
  const long cb = b * 64;

  // ---- P0: stage leaf h/c + all level vocab ids ----
  {
    const int r = (tid & 127) >> 1, half = tid & 1;
    const size_t vc = (size_t)sen[o5 + cb + r];
    if (tid < 128) {
      const u16* hs = Hl + vc * 128;
#pragma unroll
      for (int ii = 0; ii < 8; ii++) {
        const int c16 = half * 8 + ii;
        *reinterpret_cast<uint4*>(&bufH0[swz128(r, c16)]) =
            *reinterpret_cast<const uint4*>(hs + c16 * 8);
      }
    } else {
      const u16* cs = Cl + vc * 128;
#pragma unroll
      for (int ii = 0; ii < 8; ii++) {
        const int c16 = half * 8 + ii;
        *reinterpret_cast<uint4*>(&cbuf[swz128(r, c16)]) =
            *reinterpret_cast<const uint4*>(cs + c16 * 8);
      }
    }
    if (tid < 64)        sidL4[tid]       = sen[o4 + cb + tid];
    else if (tid < 96)   sidL3[tid - 64]  = sen[o3 + b * 32 + (tid - 64)];
    else if (tid < 112)  sidL2[tid - 96]  = sen[o2 + b * 16 + (tid - 96)];
    else if (tid < 116)  sidL1[tid - 112] = sen[o1 + b * 4 + (tid - 112)];
    else if (tid == 116) sidL0v[0]        = sen[o0 + b];
  }
  __syncthreads();

  const int lane = tid & 63, w = tid >> 6, l16 = lane & 15, quad = lane >> 4;

  // ---- P1 (L4, ratio 1): act(bufH0@W_*h + Ep[vp]); c in-place in cbuf; h -> bufH1 ----
#define LDE(I,R2) (*reinterpret_cast<const ushort4*>( \
    Ep + (size_t)sidL4[(I) * 16 + quad * 4 + (R2)] * 512 + col * 4))
#define EPI1(R2, E) { \
    const int row = rbase + (R2); \
    const float iv = sigmoidf_(aI[R2] + bf2f((E).x)); \
    const float uv = tanhf_   (aU[R2] + bf2f((E).y)); \
    const float ov = sigmoidf_(aO[R2] + bf2f((E).z)); \
    const float fv = sigmoidf_(aF[R2] + bf2f((E).w)); \
    const int sl = swze(row, col); \
    const float c4 = fmaf(iv, uv, fv * bf2f(cbuf[sl])); \
    const float h4 = ov * tanhf_(c4); \
    cbuf[sl] = f2bf(c4); \
    bufH1[sl] = f2bf(h4); \
  }
#pragma unroll
  for (int gl = 0; gl < 2; gl++) {
    const int col = w * 32 + gl * 16 + l16;
    ushort4 e0 = LDE(0, 0), e1 = LDE(0, 1), e2 = LDE(0, 2), e3 = LDE(0, 3);
    bf16x8 hI[4], hU[4], hO[4], hF[4];
#pragma unroll
    for (int ks = 0; ks < 4; ks++) {
      const size_t ho = (size_t)col * 128 + ks * 32 + quad * 8;
      hI[ks] = *reinterpret_cast<const bf16x8*>(BihT + ho);
      hU[ks] = *reinterpret_cast<const bf16x8*>(BuhT + ho);
      hO[ks] = *reinterpret_cast<const bf16x8*>(BohT + ho);
      hF[ks] = *reinterpret_cast<const bf16x8*>(BfT  + ho);
    }
#pragma unroll
    for (int i = 0; i < 4; i++) {
      ushort4 n0 = e0, n1 = e1, n2 = e2, n3 = e3;
      if (i + 1 < 4) {
        n0 = LDE(i + 1, 0); n1 = LDE(i + 1, 1);
        n2 = LDE(i + 1, 2); n3 = LDE(i + 1, 3);
      }
      floatx4 aI = {0.f,0.f,0.f,0.f}, aU = {0.f,0.f,0.f,0.f};
      floatx4 aO = {0.f,0.f,0.f,0.f}, aF = {0.f,0.f,0.f,0.f};
#pragma unroll
      for (int ks = 0; ks < 4; ks++) {
        bf16x8 ah = *reinterpret_cast<const bf16x8*>(&bufH0[swz128(i * 16 + l16, ks * 4 + quad)]);
        aI = __builtin_amdgcn_mfma_f32_16x16x32_bf16(ah, hI[ks], aI, 0, 0, 0);
        aU = __builtin_amdgcn_mfma_f32_16x16x32_bf16(ah, hU[ks], aU, 0, 0, 0);
        aO = __builtin_amdgcn_mfma_f32_16x16x32_bf16(ah, hO[ks], aO, 0, 0, 0);
        aF = __builtin_amdgcn_mfma_f32_16x16x32_bf16(ah, hF[ks], aF, 0, 0, 0);
      }
      const int rbase = i * 16 + quad * 4;
      EPI1(0, e0) EPI1(1, e1) EPI1(2, e2) EPI1(3, e3)
      e0 = n0; e1 = n1; e2 = n2; e3 = n3;
    }
  }
#undef LDE
#undef EPI1
  __syncthreads();

  // ---- P2 (L3, ratio 2): children bufH1/cbuf rows 0-63 -> 32 parents; h->bufH0, c deferred ----
  {
    float tc2[16];
#define LDG(I,T) (*reinterpret_cast<const ushort4*>( \
    Ep + (size_t)sidL3[(((I) * 16 + quad * 4) >> 1) + (T)] * 512 + col * 4))
#define EPI2(I, T, G) { \
    const int rbase = (I) * 16 + quad * 4; \
    const int p = (rbase >> 1) + (T); \
    const float epf = bf2f((G).w); \
    float fsum = 0.f, isum = 0.f, usum = 0.f, osum = 0.f; \
    _Pragma("unroll") \
    for (int r2 = (T) * 2; r2 < (T) * 2 + 2; r2++) { \
      const float cch = bf2f(cbuf[swze(rbase + r2, col)]); \
      fsum += sigmoidf_(aF[r2] + epf) * cch; \
      isum += aI[r2]; usum += aU[r2]; osum += aO[r2]; \
    } \
    const float c = sigmoidf_(isum + bf2f((G).x)) * tanhf_(usum + bf2f((G).y)) + fsum; \
    const float h = sigmoidf_(osum + bf2f((G).z)) * tanhf_(c); \
    bufH0[swze(p, col)] = f2bf(h); \
    tc2[(I) * 2 + (T) + gl * 8] = c; \
  }
#pragma unroll
    for (int gl = 0; gl < 2; gl++) {
      const int col = w * 32 + gl * 16 + l16;
      ushort4 g0 = LDG(0, 0), g1 = LDG(0, 1);
      bf16x8 bF[4], bI[4], bU[4], bO[4];
#pragma unroll
      for (int ks = 0; ks < 4; ks++) {
        const size_t bo_ = (size_t)col * 128 + ks * 32 + quad * 8;
        bF[ks] = *reinterpret_cast<const bf16x8*>(BfT + bo_);
        bI[ks] = *reinterpret_cast<const bf16x8*>(BihT + bo_);
        bU[ks] = *reinterpret_cast<const bf16x8*>(BuhT + bo_);
        bO[ks] = *reinterpret_cast<const bf16x8*>(BohT + bo_);
      }
#pragma unroll
      for (int i = 0; i < 4; i++) {
        ushort4 m0 = g0, m1 = g1;
        if (i + 1 < 4) { m0 = LDG(i + 1, 0); m1 = LDG(i + 1, 1); }
        floatx4 aF = {0.f,0.f,0.f,0.f}, aI = {0.f,0.f,0.f,0.f};
        floatx4 aU = {0.f,0.f,0.f,0.f}, aO = {0.f,0.f,0.f,0.f};
#pragma unroll
        for (int ks = 0; ks < 4; ks++) {
          bf16x8 a = *reinterpret_cast<const bf16x8*>(&bufH1[swz128(i * 16 + l16, ks * 4 + quad)]);
          aF = __builtin_amdgcn_mfma_f32_16x16x32_bf16(a, bF[ks], aF, 0, 0, 0);
          aI = __builtin_amdgcn_mfma_f32_16x16x32_bf16(a, bI[ks], aI, 0, 0, 0);
          aU = __builtin_amdgcn_mfma_f32_16x16x32_bf16(a, bU[ks], aU, 0, 0, 0);
          aO = __builtin_amdgcn_mfma_f32_16x16x32_bf16(a, bO[ks], aO, 0, 0, 0);
        }
        EPI2(i, 0, g0) EPI2(i, 1, g1)
        g0 = m0; g1 = m1;
      }
    }
#undef LDG
#undef EPI2
    __syncthreads();          // all cbuf child reads done
#pragma unroll
    for (int gl = 0; gl < 2; gl++) {
      const int col = w * 32 + gl * 16 + l16;
#pragma unroll
      for (int i = 0; i < 4; i++)
#pragma unroll
        for (int t = 0; t < 2; t++)
          cbuf[swze(i * 8 + quad * 2 + t, col)] = f2bf(tc2[i * 2 + t + gl * 8]);
    }
    __syncthreads();
  }

  // ---- P3 (L2, ratio 2): children bufH0/cbuf rows 0-31 -> 16 parents; h->bufH1, c deferred ----
  {
    float tc3[8];
#pragma unroll
    for (int gl = 0; gl < 2; gl++) {
      const int col = w * 32 + gl * 16 + l16;
      bf16x8 bF[4], bI[4], bU[4], bO[4];
#pragma unroll
      for (int ks = 0; ks < 4; ks++) {
        const size_t bo_ = (size_t)col * 128 + ks * 32 + quad * 8;
        bF[ks] = *reinterpret_cast<const bf16x8*>(BfT + bo_);
        bI[ks] = *reinterpret_cast<const bf16x8*>(BihT + bo_);
        bU[ks] = *reinterpret_cast<const bf16x8*>(BuhT + bo_);
        bO[ks] = *reinterpret_cast<const bf16x8*>(BohT + bo_);
      }
#pragma unroll
      for (int i = 0; i < 2; i++) {
        floatx4 aF = {0.f,0.f,0.f,0.f}, aI = {0.f,0.f,0.f,0.f};
        floatx4 aU = {0.f,0.f,0.f,0.f}, aO = {0.f,0.f,0.f,0.f};
#pragma unroll
        for (int ks = 0; ks < 4; ks++) {
          bf16x8 a = *reinterpret_cast<const bf16x8*>(&bufH0[swz128(i * 16 + l16, ks * 4 + quad)]);
          aF = __builtin_amdgcn_mfma_f32_16x16x32_bf16(a, bF[ks], aF, 0, 0, 0);
          aI = __builtin_amdgcn_mfma_f32_16x16x32_bf16(a, bI[ks], aI, 0, 0, 0);
          aU = __builtin_amdgcn_mfma_f32_16x16x32_bf16(a, bU[ks], aU, 0, 0, 0);
          aO = __builtin_amdgcn_mfma_f32_16x16x32_bf16(a, bO[ks], aO, 0, 0, 0);
        }
        const int rbase = i * 16 + quad * 4;
#pragma unroll
        for (int t = 0; t < 2; t++) {
          const int p = (rbase >> 1) + t;
          ushort4 g4 = *reinterpret_cast<const ushort4*>(
              Ep + (size_t)sidL2[p] * 512 + col * 4);
          const float epf = bf2f(g4.w);
          float fsum = 0.f, isum = 0.f, usum = 0.f, osum = 0.f;
#pragma unroll
          for (int r2 = t * 2; r2 < t * 2 + 2; r2++) {
            const float cch = bf2f(cbuf[swze(rbase + r2, col)]);
            fsum += sigmoidf_(aF[r2] + epf) * cch;
            isum += aI[r2]; usum += aU[r2]; osum += aO[r2];
          }
          const float c = sigmoidf_(isum + bf2f(g4.x)) * tanhf_(usum + bf2f(g4.y)) + fsum;
          const float h = sigmoidf_(osum + bf2f(g4.z)) * tanhf_(c);
          bufH1[swze(p, col)] = f2bf(h);
          tc3[gl * 4 + i * 2 + t] = c;
        }
      }
    }
    __syncthreads();
#pragma unroll
    for (int gl = 0; gl < 2; gl++) {
      const int col = w * 32 + gl * 16 + l16;
#pragma unroll
      for (int i = 0; i < 2; i++)
#pragma unroll
        for (int t = 0; t < 2; t++)
          cbuf[swze(i * 8 + quad * 2 + t, col)] = f2bf(tc3[gl * 4 + i * 2 + t]);
    }
    __syncthreads();
  }

  // ---- P4 (L1, ratio 4): children bufH1/cbuf rows 0-15 -> 4 parents; h->bufH0, c deferred ----
  {
    float tc4[2];
#pragma unroll
    for (int gl = 0; gl < 2; gl++) {
      const int col = w * 32 + gl * 16 + l16;
      bf16x8 bF[4], bI[4], bU[4], bO[4];
#pragma unroll
      for (int ks = 0; ks < 4; ks++) {
        const size_t bo_ = (size_t)col * 128 + ks * 32 + quad * 8;
        bF[ks] = *reinterpret_cast<const bf16x8*>(BfT + bo_);
        bI[ks] = *reinterpret_cast<const bf16x8*>(BihT + bo_);
        bU[ks] = *reinterpret_cast<const bf16x8*>(BuhT + bo_);
        bO[ks] = *reinterpret_cast<const bf16x8*>(BohT + bo_);
      }
      floatx4 aF = {0.f,0.f,0.f,0.f}, aI = {0.f,0.f,0.f,0.f};
      floatx4 aU = {0.f,0.f,0.f,0.f}, aO = {0.f,0.f,0.f,0.f};
#pragma unroll
      for (int ks = 0; ks < 4; ks++) {
        bf16x8 a = *reinterpret_cast<const bf16x8*>(&bufH1[swz128(l16, ks * 4 + quad)]);
        aF = __builtin_amdgcn_mfma_f32_16x16x32_bf16(a, bF[ks], aF, 0, 0, 0);
        aI = __builtin_amdgcn_mfma_f32_16x16x32_bf16(a, bI[ks], aI, 0, 0, 0);
        aU = __builtin_amdgcn_mfma_f32_16x16x32_bf16(a, bU[ks], aU, 0, 0, 0);
        aO = __builtin_amdgcn_mfma_f32_16x16x32_bf16(a, bO[ks], aO, 0, 0, 0);
      }
      const int rbase = quad * 4, p = quad;
      ushort4 g4 = *reinterpret_cast<const ushort4*>(
          Ep + (size_t)sidL1[p] * 512 + col * 4);
      const float epf = bf2f(g4.w);
      float fsum = 0.f, isum = 0.f, usum = 0.f, osum = 0.f;
#pragma unroll
      for (int r2 = 0; r2 < 4; r2++) {
        const float cch = bf2f(cbuf[swze(rbase + r2, col)]);
        fsum += sigmoidf_(aF[r2] + epf) * cch;
        isum += aI[r2]; usum += aU[r2]; osum += aO[r2];
      }
      const float c = sigmoidf_(isum + bf2f(g4.x)) * tanhf_(usum + bf2f(g4.y)) + fsum;
      const float h = sigmoidf_(osum + bf2f(g4.z)) * tanhf_(c);
      bufH0[swze(p, col)] = f2bf(h);
      tc4[gl] = c;
    }
    __syncthreads();
#pragma unroll
    for (int gl = 0; gl < 2; gl++) {
      const int col = w * 32 + gl * 16 + l16;
      cbuf[swze(quad, col)] = f2bf(tc4[gl]);
    }
    __syncthreads();
  }

  // ---- P5 (L0, ratio 4): children bufH0/cbuf rows 0-3 -> 1 root; h -> global ----
  {
#pragma unroll
    for (int gl = 0; gl < 2; gl++) {
      const int col = w * 32 + gl * 16 + l16;
      bf16x8 bF[4], bI[4], bU[4], bO[4];
#pragma unroll
      for (int ks = 0; ks < 4; ks++) {
        const size_t bo_ = (size_t)col * 128 + ks * 32 + quad * 8;
        bF[ks] = *reinterpret_cast<const bf16x8*>(BfT + bo_);
        bI[ks] = *reinterpret_cast<const bf16x8*>(BihT + bo_);
        bU[ks] = *reinterpret_cast<const bf16x8*>(BuhT + bo_);
        bO[ks] = *reinterpret_cast<const bf16x8*>(BohT + bo_);
      }
      floatx4 aF = {0.f,0.f,0.f,0.f}, aI = {0.f,0.f,0.f,0.f};
      floatx4 aU = {0.f,0.f,0.f,0.f}, aO = {0.f,0.f,0.f,0.f};
#pragma unroll
      for (int ks = 0; ks < 4; ks++) {
        // rows 4-15 hold stale-but-finite values; their outputs are discarded
        bf16x8 a = *reinterpret_cast<const bf16x8*>(&bufH0[swz128(l16, ks * 4 + quad)]);
        aF = __builtin_amdgcn_mfma_f32_16x16x32_bf16(a, bF[ks], aF, 0, 0, 0);
        aI = __builtin_amdgcn_mfma_f32_16x16x32_bf16(a, bI[ks], aI, 0, 0, 0);
        aU = __builtin_amdgcn_mfma_f32_16x16x32_bf16(a, bU[ks], aU, 0, 0, 0);
        aO = __builtin_amdgcn_mfma_f32_16x16x32_bf16(a, bO[ks], aO, 0, 0, 0);
      }
      if (quad == 0) {
        ushort4 g4 = *reinterpret_cast<const ushort4*>(
            Ep + (size_t)sidL0v[0] * 512 + col * 4);
        const float epf = bf2f(g4.w);
        float fsum = 0.f, isum = 0.f, usum = 0.f, osum = 0.f;
#pragma unroll
        for (int r2 = 0; r2 < 4; r2++) {
          const float cch = bf2f(cbuf[swze(r2, col)]);
          fsum += sigmoidf_(aF[r2] + epf) * cch;
          isum += aI[r2]; usum += aU[r2]; osum += aO[r2];
        }
        const float c = sigmoidf_(isum + bf2f(g4.x)) * tanhf_(usum + bf2f(g4.y)) + fsum;
        const float h = sigmoidf_(osum + bf2f(g4.z)) * tanhf_(c);
        h_root[b * 128 + col] = f2bf(h);
      }
    }
  }
}

// ---------- fused weight/bias prep ----------
__global__ void build_prep(
    const float* __restrict__ Wix, const float* __restrict__ Wux,
    const float* __restrict__ Wox, const float* __restrict__ Wfx,
    const float* __restrict__ Wih, const float* __restrict__ Wuh,
    const float* __restrict__ Woh, const float* __restrict__ Wfh,
    const float* __restrict__ b_ix, const float* __restrict__ b_ih,
    const float* __restrict__ b_ux, const float* __restrict__ b_uh,
    const float* __restrict__ b_ox, const float* __restrict__ b_oh,
    const float* __restrict__ b_fx, const float* __restrict__ b_fh,
    u16* __restrict__ WT, u16* __restrict__ BihT, u16* __restrict__ BuhT,
    u16* __restrict__ BohT, u16* __restrict__ BfhT, float* __restrict__ bsum)
{
  const int idx = blockIdx.x * 256 + threadIdx.x;
  if (idx < 65536) {                       // WallT: [g*128+j][k] = Wx[k][j]
    int n = idx >> 7, k = idx & 127;
    int g = n >> 7, j = n & 127;
    const float* W = (g == 0) ? Wix : (g == 1) ? Wux : (g == 2) ? Wox : Wfx;
    WT[idx] = f2bf(W[k * 128 + j]);
  } else if (idx < 131072) {               // 4 x BT128: [n][k] = Wh[k][n]
    int t = idx - 65536;
    int tb = t >> 14, i2 = t & 16383;
    int n = i2 >> 7, k = i2 & 127;
    const float* W = (tb == 0) ? Wih : (tb == 1) ? Wuh : (tb == 2) ? Woh : Wfh;
    u16* BT = (tb == 0) ? BihT : (tb == 1) ? BuhT : (tb == 2) ? BohT : BfhT;
    BT[i2] = f2bf(W[k * 128 + n]);
  } else if (idx < 131584) {               // bsum
    int s = idx - 131072;
    int g = s >> 7, j = s & 127;
    float v = (g == 0) ? b_ix[j] + b_ih[j] : (g == 1) ? b_ux[j] + b_uh[j]
            : (g == 2) ? b_ox[j] + b_oh[j] : b_fx[j] + b_fh[j];
    bsum[s] = v;
  }
}

// ---------- output projection (4096 x 4, tiny) ----------
__global__ void out_proj(const u16* __restrict__ h_root, const float* __restrict__ W_out,
                         const float* __restrict__ b_out, float* __restrict__ out)
{
  int idx = blockIdx.x * 256 + threadIdx.x;   // 4096*4
  int n = idx >> 2, cls = idx & 3;
  float s = b_out[cls];
  for (int k = 0; k < 128; k++)
    s += bf2f(h_root[(long)n * 128 + k]) * W_out[k * 4 + cls];
  out[idx] = s;
}

extern "C" void kernel_launch(void* const* d_in, const int* in_sizes, int n_in,
                              void* d_out, int out_size, void* d_ws, size_t ws_size,
                              hipStream_t stream)
{
  const int*   sen  = (const int*)d_in[0];
  const float* emb  = (const float*)d_in[1];
  const float* W_ix = (const float*)d_in[2];  const float* b_ix = (const float*)d_in[3];
  const float* W_ih = (const float*)d_in[4];  const float* b_ih = (const float*)d_in[5];
  const float* W_fx = (const float*)d_in[6];  const float* b_fx = (const float*)d_in[7];
  const float* W_fh = (const float*)d_in[8];  const float* b_fh = (const float*)d_in[9];
  const float* W_ox = (const float*)d_in[10]; const float* b_ox = (const float*)d_in[11];
  const float* W_oh = (const float*)d_in[12]; const float* b_oh = (const float*)d_in[13];
  const float* W_ux = (const float*)d_in[14]; const float* b_ux = (const float*)d_in[15];
  const float* W_uh = (const float*)d_in[16]; const float* b_uh = (const float*)d_in[17];
  const float* W_out= (const float*)d_in[18]; const float* b_out= (const float*)d_in[19];
  float* out = (float*)d_out;

  // ---- workspace ----
  const size_t EPB = (size_t)50000 * 512 * 2;       // Ep (51.2 MB)
  const size_t TBB = (size_t)50000 * 128 * 2;       // Hl / Cl (12.8 MB each)
  const size_t HRB = (size_t)4096 * 128 * 2;        // root h (1 MB)
  const size_t need = EPB + 2 * TBB + HRB
                    + (size_t)512 * 128 * 2 + 4 * (size_t)128 * 128 * 2 + 512 * 4 + 8192;
  fprintf(stderr, "[tree_lstm] ws_size=%zu need=%zu\n", ws_size, need);
  if (ws_size < need) {
    fprintf(stderr, "[tree_lstm] INSUFFICIENT WORKSPACE — skipping launch\n");
    return;
  }
  char* ws = (char*)d_ws;
  size_t off = 0;
  auto take = [&](size_t bytes) { char* p = ws + off; off += (bytes + 255) & ~(size_t)255; return p; };
  u16* Ep = (u16*)take(EPB);
  u16* Hl = (u16*)take(TBB);
  u16* Cl = (u16*)take(TBB);
  u16* hroot = (u16*)take(HRB);
  u16* WallT = (u16*)take((size_t)512 * 128 * 2);
  u16* BihT = (u16*)take((size_t)128 * 128 * 2);
  u16* BuhT = (u16*)take((size_t)128 * 128 * 2);
  u16* BohT = (u16*)take((size_t)128 * 128 * 2);
  u16* BfhT = (u16*)take((size_t)128 * 128 * 2);
  float* bsum = (float*)take(512 * 4);

  // ---- prep ----
  build_prep<<<514, 256, 0, stream>>>(W_ix, W_ux, W_ox, W_fx, W_ih, W_uh, W_oh, W_fh,
      b_ix, b_ih, b_ux, b_uh, b_ox, b_oh, b_fx, b_fh,
      WallT, BihT, BuhT, BohT, BfhT, bsum);
  proj_e<<<391, 256, 0, stream>>>(emb, WallT, bsum, Ep, Hl, Cl);

  const long LOFF[6] = {0, 4096, 20480, 86016, 217088, 479232};

  // whole tree: one block per L0 subtree (L4->L3->L2->L1->L0 all in LDS)
  k_tree<<<4096, 256, 0, stream>>>(sen, Ep, Hl, Cl,
      BfhT, BihT, BuhT, BohT, hroot,
      LOFF[0], LOFF[1], LOFF[2], LOFF[3], LOFF[4], LOFF[5]);

  out_proj<<<64, 256, 0, stream>>>(hroot, W_out, b_out, out);
}

// Round 16
// 470.392 us; speedup vs baseline: 1.2310x; 1.2310x over previous
//
#include <hip/hip_runtime.h>
#include <hip/hip_bf16.h>
#include <cstdio>

typedef unsigned short u16;
typedef __bf16 bf16x8 __attribute__((ext_vector_type(8)));
typedef float  floatx4 __attribute__((ext_vector_type(4)));

// ---------- scalar helpers ----------
__device__ __forceinline__ float bf2f(u16 u) {
  union { unsigned int i; float f; } v; v.i = ((unsigned int)u) << 16; return v.f;
}
__device__ __forceinline__ u16 f2bf(float f) {
  union { float f; unsigned int i; } v; v.f = f;
  unsigned int x = v.i;
  return (u16)((x + 0x7fffu + ((x >> 16) & 1u)) >> 16);   // RNE
}
__device__ __forceinline__ unsigned int f2bf_pk(float a, float b) {   // [lo=a, hi=b]
  __hip_bfloat162 h = __float22bfloat162_rn(make_float2(a, b));
  union { __hip_bfloat162 h; unsigned int u; } v; v.h = h; return v.u;
}
// fast gates: v_rcp (~1 ulp) + native exp — no IEEE div
__device__ __forceinline__ float sigmoidf_(float x) {
  return __builtin_amdgcn_rcpf(1.f + __expf(-x));
}
__device__ __forceinline__ float tanhf_(float x) {
  return fmaf(-2.f, __builtin_amdgcn_rcpf(1.f + __expf(2.f * x)), 1.f);
}

// LDS swizzle, 128-elem rows, 16B chunks: chunk' = chunk ^ (row&15)
__device__ __forceinline__ int swz128(int row, int c16) {
  return row * 128 + ((c16 ^ (row & 15)) << 3);
}
// element-level access into swizzled rows
__device__ __forceinline__ int swze(int row, int col) {
  return row * 128 + (((((col >> 3)) ^ (row & 15)) << 3) | (col & 7));
}

// ============ proj_e: Ep[v][col][4] = {i,u,o,f} pre-acts + biases, + fused leaf h/c ============
__global__ __launch_bounds__(256, 2) void proj_e(
    const float* __restrict__ emb, const u16* __restrict__ WT,
    const float* __restrict__ bsum, u16* __restrict__ Ep,
    u16* __restrict__ Hl, u16* __restrict__ Cl)
{
  __shared__ __align__(16) u16 ldsA[128 * 128];
  const int tid = threadIdx.x;
  const long m0 = (long)blockIdx.x * 128;
  {
    const int r = tid >> 1, half = tid & 1;
    long row = m0 + r; if (row > 49999) row = 49999;
    const float* src = emb + row * 128 + half * 64;
#pragma unroll
    for (int i = 0; i < 8; i++) {
      float4 v0 = *reinterpret_cast<const float4*>(src + i * 8);
      float4 v1 = *reinterpret_cast<const float4*>(src + i * 8 + 4);
      unsigned int ov[4] = { f2bf_pk(v0.x, v0.y), f2bf_pk(v0.z, v0.w),
                             f2bf_pk(v1.x, v1.y), f2bf_pk(v1.z, v1.w) };
      *reinterpret_cast<uint4*>(&ldsA[swz128(r, half * 8 + i)]) =
          *reinterpret_cast<const uint4*>(ov);
    }
  }
  __syncthreads();
  const int lane = tid & 63, w = tid >> 6, l16 = lane & 15, quad = lane >> 4;
#pragma unroll
  for (int half = 0; half < 2; half++) {
    const int col = w * 32 + half * 16 + l16;
    bf16x8 bI[4], bU[4], bO[4], bF[4];
#pragma unroll
    for (int ks = 0; ks < 4; ks++) {
      const size_t o_ = ks * 32 + quad * 8;
      bI[ks] = *reinterpret_cast<const bf16x8*>(WT + (size_t)(0   + col) * 128 + o_);
      bU[ks] = *reinterpret_cast<const bf16x8*>(WT + (size_t)(128 + col) * 128 + o_);
      bO[ks] = *reinterpret_cast<const bf16x8*>(WT + (size_t)(256 + col) * 128 + o_);
      bF[ks] = *reinterpret_cast<const bf16x8*>(WT + (size_t)(384 + col) * 128 + o_);
    }
    const float bi = bsum[col], bu = bsum[128 + col], bo = bsum[256 + col], bf = bsum[384 + col];
#pragma unroll
    for (int i = 0; i < 8; i++) {
      floatx4 aI = {0.f,0.f,0.f,0.f}, aU = {0.f,0.f,0.f,0.f};
      floatx4 aO = {0.f,0.f,0.f,0.f}, aF = {0.f,0.f,0.f,0.f};
#pragma unroll
      for (int ks = 0; ks < 4; ks++) {
        bf16x8 a = *reinterpret_cast<const bf16x8*>(&ldsA[swz128(i * 16 + l16, ks * 4 + quad)]);
        aI = __builtin_amdgcn_mfma_f32_16x16x32_bf16(a, bI[ks], aI, 0, 0, 0);
        aU = __builtin_amdgcn_mfma_f32_16x16x32_bf16(a, bU[ks], aU, 0, 0, 0);
        aO = __builtin_amdgcn_mfma_f32_16x16x32_bf16(a, bO[ks], aO, 0, 0, 0);
        aF = __builtin_amdgcn_mfma_f32_16x16x32_bf16(a, bF[ks], aF, 0, 0, 0);
      }
#pragma unroll
      for (int r2 = 0; r2 < 4; r2++) {
        const long row = m0 + i * 16 + quad * 4 + r2;
        if (row < 50000) {
          u16 ov[4] = { f2bf(aI[r2] + bi), f2bf(aU[r2] + bu),
                        f2bf(aO[r2] + bo), f2bf(aF[r2] + bf) };
          *reinterpret_cast<ushort4*>(Ep + row * 512 + col * 4) =
              *reinterpret_cast<const ushort4*>(ov);
          // fused leaf activations from the stored bf16 values
          const float cv = sigmoidf_(bf2f(ov[0])) * tanhf_(bf2f(ov[1]));
          const float hv = sigmoidf_(bf2f(ov[2])) * tanhf_(cv);
          Cl[row * 128 + col] = f2bf(cv);
          Hl[row * 128 + col] = f2bf(hv);
        }
      }
    }
  }
}

// ============ k_l3fused v6: R10 structure + FULLY pre-issued gather schedule ============
// Occupancy budget: LDS 48.6KB -> 3 blocks/CU -> 3 waves/SIMD; the 3-wave VGPR tier
// extends to ~170 regs, current use 124 -> ~45 regs FREE. Spend them: all 16 phase-1
// e4 reads and all 8 phase-2 g4 reads issue up front as NAMED ushort4s (no arrays -
// R9's scratch-spill lesson) before weights+MFMAs -> 16 misses in flight per wave.
// Bit-identical values; pure reorder. Spill check: WRITE_SIZE must stay ~69 MB.
__global__ __launch_bounds__(256, 2) void k_l3fused(
    const int* __restrict__ sen, const u16* __restrict__ Ep,
    const u16* __restrict__ Hl, const u16* __restrict__ Cl,
    const u16* __restrict__ BfT, const u16* __restrict__ BihT,
    const u16* __restrict__ BuhT, const u16* __restrict__ BohT,
    u16* __restrict__ c_out, u16* __restrict__ h_out,
    long o0, long o1, long o2)
{
  constexpr int PM = 32, CM = 64;
  __shared__ __align__(16) u16 ldsH[CM * 128];   // leaf h (swz) 16 KB
  __shared__ __align__(16) u16 ldsC[CM * 128];   // leaf c -> L4 c in place (swz) 16 KB
  __shared__ __align__(16) u16 ldsA[CM * 128];   // L4 h (swz) 16 KB
  __shared__ int sidC[CM];                       // L4-node vocab ids
  __shared__ int sidP[PM];                       // L3-parent vocab ids

  const int tid = threadIdx.x;
  const long p0 = (long)blockIdx.x * PM;
  const long cb = (long)blockIdx.x * CM;

  // ---- phase 0: stage Hl/Cl (2 threads/row/table, 8 uint4 each) ----
  {
    const int r = (tid & 127) >> 1, half = tid & 1;
    const size_t vc = (size_t)sen[o2 + cb + r];
    if (tid < 128) {
      const u16* hs = Hl + vc * 128;
#pragma unroll
      for (int ii = 0; ii < 8; ii++) {
        const int c16 = half * 8 + ii;
        *reinterpret_cast<uint4*>(&ldsH[swz128(r, c16)]) =
            *reinterpret_cast<const uint4*>(hs + c16 * 8);
      }
    } else {
      const u16* cs = Cl + vc * 128;
#pragma unroll
      for (int ii = 0; ii < 8; ii++) {
        const int c16 = half * 8 + ii;
        *reinterpret_cast<uint4*>(&ldsC[swz128(r, c16)]) =
            *reinterpret_cast<const uint4*>(cs + c16 * 8);
      }
    }
    if (tid < CM) sidC[tid] = sen[o1 + cb + tid];
    if (tid < PM) sidP[tid] = sen[o0 + p0 + tid];
  }
  __syncthreads();

  const int lane = tid & 63, w = tid >> 6, l16 = lane & 15, quad = lane >> 4;

  // ---- phase 1: L4 = act(Hl@W_*h + Ep[vp]) ; c4/h4 into LDS ----
#define LDE(I,R2) (*reinterpret_cast<const ushort4*>( \
    Ep + (size_t)sidC[(I) * 16 + quad * 4 + (R2)] * 512 + col * 4))
#define EPI1(R2, E) { \
    const int row = rbase + (R2); \
    const float iv = sigmoidf_(aI[R2] + bf2f((E).x)); \
    const float uv = tanhf_   (aU[R2] + bf2f((E).y)); \
    const float ov = sigmoidf_(aO[R2] + bf2f((E).z)); \
    const float fv = sigmoidf_(aF[R2] + bf2f((E).w)); \
    const int sl = swze(row, col); \
    const float c4 = fmaf(iv, uv, fv * bf2f(ldsC[sl])); \
    const float h4 = ov * tanhf_(c4); \
    ldsC[sl] = f2bf(c4); \
    ldsA[sl] = f2bf(h4); \
  }
#define TILE1(I, EA, EB, EC, ED) { \
    floatx4 aI = {0.f,0.f,0.f,0.f}, aU = {0.f,0.f,0.f,0.f}; \
    floatx4 aO = {0.f,0.f,0.f,0.f}, aF = {0.f,0.f,0.f,0.f}; \
    _Pragma("unroll") \
    for (int ks = 0; ks < 4; ks++) { \
      bf16x8 ah = *reinterpret_cast<const bf16x8*>(&ldsH[swz128((I) * 16 + l16, ks * 4 + quad)]); \
      aI = __builtin_amdgcn_mfma_f32_16x16x32_bf16(ah, hI[ks], aI, 0, 0, 0); \
      aU = __builtin_amdgcn_mfma_f32_16x16x32_bf16(ah, hU[ks], aU, 0, 0, 0); \
      aO = __builtin_amdgcn_mfma_f32_16x16x32_bf16(ah, hO[ks], aO, 0, 0, 0); \
      aF = __builtin_amdgcn_mfma_f32_16x16x32_bf16(ah, hF[ks], aF, 0, 0, 0); \
    } \
    const int rbase = (I) * 16 + quad * 4; \
    EPI1(0, EA) EPI1(1, EB) EPI1(2, EC) EPI1(3, ED) \
  }
#pragma unroll
  for (int gl = 0; gl < 2; gl++) {
    const int col = w * 32 + gl * 16 + l16;
    // pre-issue ALL 16 x-side preact reads for this gl
    ushort4 e00 = LDE(0, 0), e01 = LDE(0, 1), e02 = LDE(0, 2), e03 = LDE(0, 3);
    ushort4 e10 = LDE(1, 0), e11 = LDE(1, 1), e12 = LDE(1, 2), e13 = LDE(1, 3);
    ushort4 e20 = LDE(2, 0), e21 = LDE(2, 1), e22 = LDE(2, 2), e23 = LDE(2, 3);
    ushort4 e30 = LDE(3, 0), e31 = LDE(3, 1), e32 = LDE(3, 2), e33 = LDE(3, 3);
    bf16x8 hI[4], hU[4], hO[4], hF[4];
#pragma unroll
    for (int ks = 0; ks < 4; ks++) {
      const size_t ho = (size_t)col * 128 + ks * 32 + quad * 8;
      hI[ks] = *reinterpret_cast<const bf16x8*>(BihT + ho);
      hU[ks] = *reinterpret_cast<const bf16x8*>(BuhT + ho);
      hO[ks] = *reinterpret_cast<const bf16x8*>(BohT + ho);
      hF[ks] = *reinterpret_cast<const bf16x8*>(BfT  + ho);
    }
    TILE1(0, e00, e01, e02, e03)
    TILE1(1, e10, e11, e12, e13)
    TILE1(2, e20, e21, e22, e23)
    TILE1(3, e30, e31, e32, e33)
  }
#undef LDE
#undef EPI1
#undef TILE1
  __syncthreads();

  // ---- phase 2: L3 tree-LSTM step ----
#define LDG(I,T) (*reinterpret_cast<const ushort4*>( \
    Ep + (size_t)sidP[(((I) * 16 + quad * 4) >> 1) + (T)] * 512 + col * 4))
#define EPI2(T, G) { \
    const int p = (rbase >> 1) + (T); \
    const float epf = bf2f((G).w); \
    float fsum = 0.f, isum = 0.f, usum = 0.f, osum = 0.f; \
    _Pragma("unroll") \
    for (int r2 = (T) * 2; r2 < (T) * 2 + 2; r2++) { \
      const int row = rbase + r2; \
      const float cch = bf2f(ldsC[swze(row, col)]); \
      fsum += sigmoidf_(aF[r2] + epf) * cch; \
      isum += aI[r2]; usum += aU[r2]; osum += aO[r2]; \
    } \
    const float c = sigmoidf_(isum + bf2f((G).x)) * tanhf_(usum + bf2f((G).y)) + fsum; \
    const float h = sigmoidf_(osum + bf2f((G).z)) * tanhf_(c); \
    c_out[(p0 + p) * 128 + col] = f2bf(c); \
    h_out[(p0 + p) * 128 + col] = f2bf(h); \
  }
#define TILE2(I, GA, GB) { \
    floatx4 aF = {0.f,0.f,0.f,0.f}, aI = {0.f,0.f,0.f,0.f}; \
    floatx4 aU = {0.f,0.f,0.f,0.f}, aO = {0.f,0.f,0.f,0.f}; \
    _Pragma("unroll") \
    for (int ks = 0; ks < 4; ks++) { \
      bf16x8 a = *reinterpret_cast<const bf16x8*>(&ldsA[swz128((I) * 16 + l16, ks * 4 + quad)]); \
      aF = __builtin_amdgcn_mfma_f32_16x16x32_bf16(a, bF[ks], aF, 0, 0, 0); \
      aI = __builtin_amdgcn_mfma_f32_16x16x32_bf16(a, bI[ks], aI, 0, 0, 0); \
      aU = __builtin_amdgcn_mfma_f32_16x16x32_bf16(a, bU[ks], aU, 0, 0, 0); \
      aO = __builtin_amdgcn_mfma_f32_16x16x32_bf16(a, bO[ks], aO, 0, 0, 0); \
    } \
    const int rbase = (I) * 16 + quad * 4; \
    EPI2(0, GA) EPI2(1, GB) \
  }
#pragma unroll
  for (int gl = 0; gl < 2; gl++) {
    const int col = w * 32 + gl * 16 + l16;
    // pre-issue ALL 8 parent preact reads for this gl
    ushort4 g00 = LDG(0, 0), g01 = LDG(0, 1);
    ushort4 g10 = LDG(1, 0), g11 = LDG(1, 1);
    ushort4 g20 = LDG(2, 0), g21 = LDG(2, 1);
    ushort4 g30 = LDG(3, 0), g31 = LDG(3, 1);
    bf16x8 bF[4], bI[4], bU[4], bO[4];
#pragma unroll
    for (int ks = 0; ks < 4; ks++) {
      const size_t bo_ = (size_t)col * 128 + ks * 32 + quad * 8;
      bF[ks] = *reinterpret_cast<const bf16x8*>(BfT + bo_);
      bI[ks] = *reinterpret_cast<const bf16x8*>(BihT + bo_);
      bU[ks] = *reinterpret_cast<const bf16x8*>(BuhT + bo_);
      bO[ks] = *reinterpret_cast<const bf16x8*>(BohT + bo_);
    }
    TILE2(0, g00, g01)
    TILE2(1, g10, g11)
    TILE2(2, g20, g21)
    TILE2(3, g30, g31)
  }
#undef LDG
#undef EPI2
#undef TILE2
}

// ============ k_level: per-i-tile fused f/i/u/o (inner levels, computed children) ============
template<int LR>
__global__ __launch_bounds__(256, 2) void k_level(
    const int* __restrict__ sen, const u16* __restrict__ Ep,
    const u16* __restrict__ h_prev, const u16* __restrict__ c_prev,
    const u16* __restrict__ BfT, const u16* __restrict__ BihT,
    const u16* __restrict__ BuhT, const u16* __restrict__ BohT,
    u16* __restrict__ c_out, u16* __restrict__ h_out,
    long o0)
{
  constexpr int PM  = (LR == 2) ? 32 : 64;
  constexpr int CM  = PM << LR;
  constexpr int NCI = CM / 16;
  constexpr int RT  = 1 << LR;
  constexpr int RTI = 4 >> LR;         // parents per 4-row quad block
  constexpr int TPR = 256 / CM;        // staging threads per child row
  __shared__ __align__(16) u16 ldsA[CM * 128];   // child h (swz)
  __shared__ int sidP[PM];

  const int tid = threadIdx.x;
  const long p0 = (long)blockIdx.x * PM;
  const long cb = (long)blockIdx.x * CM;

  // ---- stage children ----
  {
    const int r = tid / TPR, q = tid % TPR;
    constexpr int CH = 16 / TPR;
    const u16* src = h_prev + (cb + r) * 128;
#pragma unroll
    for (int ii = 0; ii < CH; ii++) {
      const int c16 = q * CH + ii;
      *reinterpret_cast<uint4*>(&ldsA[swz128(r, c16)]) =
          *reinterpret_cast<const uint4*>(src + c16 * 8);
    }
    if (tid < PM) sidP[tid] = sen[o0 + p0 + tid];
  }
  __syncthreads();

  const int lane = tid & 63, w = tid >> 6, l16 = lane & 15, quad = lane >> 4;

#pragma unroll
  for (int gl = 0; gl < 2; gl++) {
    const int col = w * 32 + gl * 16 + l16;
    bf16x8 bF[4], bI[4], bU[4], bO[4];
#pragma unroll
    for (int ks = 0; ks < 4; ks++) {
      const size_t bo_ = (size_t)col * 128 + ks * 32 + quad * 8;
      bF[ks] = *reinterpret_cast<const bf16x8*>(BfT + bo_);
      bI[ks] = *reinterpret_cast<const bf16x8*>(BihT + bo_);
      bU[ks] = *reinterpret_cast<const bf16x8*>(BuhT + bo_);
      bO[ks] = *reinterpret_cast<const bf16x8*>(BohT + bo_);
    }
#pragma unroll
    for (int i = 0; i < NCI; i++) {
      const int rbase = i * 16 + quad * 4;
      // prefetch epilogue operands before the MFMA chain
      ushort4 g4p[RTI];
      u16 cch16[RTI][RT];
#pragma unroll
      for (int t = 0; t < RTI; t++) {
        g4p[t] = *reinterpret_cast<const ushort4*>(
            Ep + (size_t)sidP[(rbase >> LR) + t] * 512 + col * 4);
#pragma unroll
        for (int r2 = 0; r2 < RT; r2++)
          cch16[t][r2] = c_prev[(cb + rbase + t * RT + r2) * 128 + col];
      }
      floatx4 aF = {0.f,0.f,0.f,0.f}, aI = {0.f,0.f,0.f,0.f};
      floatx4 aU = {0.f,0.f,0.f,0.f}, aO = {0.f,0.f,0.f,0.f};
#pragma unroll
      for (int ks = 0; ks < 4; ks++) {
        bf16x8 a = *reinterpret_cast<const bf16x8*>(&ldsA[swz128(i * 16 + l16, ks * 4 + quad)]);
        aF = __builtin_amdgcn_mfma_f32_16x16x32_bf16(a, bF[ks], aF, 0, 0, 0);
        aI = __builtin_amdgcn_mfma_f32_16x16x32_bf16(a, bI[ks], aI, 0, 0, 0);
        aU = __builtin_amdgcn_mfma_f32_16x16x32_bf16(a, bU[ks], aU, 0, 0, 0);
        aO = __builtin_amdgcn_mfma_f32_16x16x32_bf16(a, bO[ks], aO, 0, 0, 0);
      }
#pragma unroll
      for (int t = 0; t < RTI; t++) {
        const int p = (rbase >> LR) + t;
        const ushort4 g4 = g4p[t];
        const float epf = bf2f(g4.w);
        float fsum = 0.f, isum = 0.f, usum = 0.f, osum = 0.f;
#pragma unroll
        for (int r2 = t * RT; r2 < t * RT + RT; r2++) {
          const float cch = bf2f(cch16[t][r2 - t * RT]);
          fsum += sigmoidf_(aF[r2] + epf) * cch;
          isum += aI[r2]; usum += aU[r2]; osum += aO[r2];
        }
        const float c = sigmoidf_(isum + bf2f(g4.x)) * tanhf_(usum + bf2f(g4.y)) + fsum;
        const float h = sigmoidf_(osum + bf2f(g4.z)) * tanhf_(c);
        c_out[(p0 + p) * 128 + col] = f2bf(c);
        h_out[(p0 + p) * 128 + col] = f2bf(h);
      }
    }
  }
}

// ---------- fused weight/bias prep ----------
__global__ void build_prep(
    const float* __restrict__ Wix, const float* __restrict__ Wux,
    const float* __restrict__ Wox, const float* __restrict__ Wfx,
    const float* __restrict__ Wih, const float* __restrict__ Wuh,
    const float* __restrict__ Woh, const float* __restrict__ Wfh,
    const float* __restrict__ b_ix, const float* __restrict__ b_ih,
    const float* __restrict__ b_ux, const float* __restrict__ b_uh,
    const float* __restrict__ b_ox, const float* __restrict__ b_oh,
    const float* __restrict__ b_fx, const float* __restrict__ b_fh,
    u16* __restrict__ WT, u16* __restrict__ BihT, u16* __restrict__ BuhT,
    u16* __restrict__ BohT, u16* __restrict__ BfhT, float* __restrict__ bsum)
{
  const int idx = blockIdx.x * 256 + threadIdx.x;
  if (idx < 65536) {                       // WallT: [g*128+j][k] = Wx[k][j]
    int n = idx >> 7, k = idx & 127;
    int g = n >> 7, j = n & 127;
    const float* W = (g == 0) ? Wix : (g == 1) ? Wux : (g == 2) ? Wox : Wfx;
    WT[idx] = f2bf(W[k * 128 + j]);
  } else if (idx < 131072) {               // 4 x BT128: [n][k] = Wh[k][n]
    int t = idx - 65536;
    int tb = t >> 14, i2 = t & 16383;
    int n = i2 >> 7, k = i2 & 127;
    const float* W = (tb == 0) ? Wih : (tb == 1) ? Wuh : (tb == 2) ? Woh : Wfh;
    u16* BT = (tb == 0) ? BihT : (tb == 1) ? BuhT : (tb == 2) ? BohT : BfhT;
    BT[i2] = f2bf(W[k * 128 + n]);
  } else if (idx < 131584) {               // bsum
    int s = idx - 131072;
    int g = s >> 7, j = s & 127;
    float v = (g == 0) ? b_ix[j] + b_ih[j] : (g == 1) ? b_ux[j] + b_uh[j]
            : (g == 2) ? b_ox[j] + b_oh[j] : b_fx[j] + b_fh[j];
    bsum[s] = v;
  }
}

// ---------- output projection (4096 x 4, tiny) ----------
__global__ void out_proj(const u16* __restrict__ h_root, const float* __restrict__ W_out,
                         const float* __restrict__ b_out, float* __restrict__ out)
{
  int idx = blockIdx.x * 256 + threadIdx.x;   // 4096*4
  int n = idx >> 2, cls = idx & 3;
  float s = b_out[cls];
  for (int k = 0; k < 128; k++)
    s += bf2f(h_root[(long)n * 128 + k]) * W_out[k * 4 + cls];
  out[idx] = s;
}

extern "C" void kernel_launch(void* const* d_in, const int* in_sizes, int n_in,
                              void* d_out, int out_size, void* d_ws, size_t ws_size,
                              hipStream_t stream)
{
  const int*   sen  = (const int*)d_in[0];
  const float* emb  = (const float*)d_in[1];
  const float* W_ix = (const float*)d_in[2];  const float* b_ix = (const float*)d_in[3];
  const float* W_ih = (const float*)d_in[4];  const float* b_ih = (const float*)d_in[5];
  const float* W_fx = (const float*)d_in[6];  const float* b_fx = (const float*)d_in[7];
  const float* W_fh = (const float*)d_in[8];  const float* b_fh = (const float*)d_in[9];
  const float* W_ox = (const float*)d_in[10]; const float* b_ox = (const float*)d_in[11];
  const float* W_oh = (const float*)d_in[12]; const float* b_oh = (const float*)d_in[13];
  const float* W_ux = (const float*)d_in[14]; const float* b_ux = (const float*)d_in[15];
  const float* W_uh = (const float*)d_in[16]; const float* b_uh = (const float*)d_in[17];
  const float* W_out= (const float*)d_in[18]; const float* b_out= (const float*)d_in[19];
  float* out = (float*)d_out;

  // ---- workspace ----
  const size_t EPB = (size_t)50000 * 512 * 2;       // Ep (51.2 MB)
  const size_t TBB = (size_t)50000 * 128 * 2;       // Hl / Cl (12.8 MB each)
  const size_t H3  = (size_t)131072 * 128 * 2;      // 33.55 MB each
  const size_t H2  = (size_t)65536  * 128 * 2;
  const size_t H1  = (size_t)16384  * 128 * 2;
  const size_t H0  = (size_t)4096   * 128 * 2;
  const size_t need = EPB + 2 * TBB + 2 * (H3 + H2 + H1 + H0)
                    + (size_t)512 * 128 * 2 + 4 * (size_t)128 * 128 * 2 + 512 * 4 + 8192;
  fprintf(stderr, "[tree_lstm] ws_size=%zu need=%zu\n", ws_size, need);
  if (ws_size < need) {
    fprintf(stderr, "[tree_lstm] INSUFFICIENT WORKSPACE — skipping launch\n");
    return;
  }
  char* ws = (char*)d_ws;
  size_t off = 0;
  auto take = [&](size_t bytes) { char* p = ws + off; off += (bytes + 255) & ~(size_t)255; return p; };
  u16* Ep = (u16*)take(EPB);
  u16* Hl = (u16*)take(TBB);
  u16* Cl = (u16*)take(TBB);
  u16* h3 = (u16*)take(H3);  u16* c3 = (u16*)take(H3);
  u16* h2 = (u16*)take(H2);  u16* c2 = (u16*)take(H2);
  u16* h1 = (u16*)take(H1);  u16* c1 = (u16*)take(H1);
  u16* h0 = (u16*)take(H0);  u16* c0 = (u16*)take(H0);
  u16* WallT = (u16*)take((size_t)512 * 128 * 2);
  u16* BihT = (u16*)take((size_t)128 * 128 * 2);
  u16* BuhT = (u16*)take((size_t)128 * 128 * 2);
  u16* BohT = (u16*)take((size_t)128 * 128 * 2);
  u16* BfhT = (u16*)take((size_t)128 * 128 * 2);
  float* bsum = (float*)take(512 * 4);

  // ---- prep ----
  build_prep<<<514, 256, 0, stream>>>(W_ix, W_ux, W_ox, W_fx, W_ih, W_uh, W_oh, W_fh,
      b_ix, b_ih, b_ux, b_uh, b_ox, b_oh, b_fx, b_fh,
      WallT, BihT, BuhT, BohT, BfhT, bsum);
  proj_e<<<391, 256, 0, stream>>>(emb, WallT, bsum, Ep, Hl, Cl);

  const long LOFF[6] = {0, 4096, 20480, 86016, 217088, 479232};

  // L3 (131072 parents, PM=32/CM=64) with L4 computed in-kernel
  k_l3fused<<<4096, 256, 0, stream>>>(sen, Ep, Hl, Cl,
      BfhT, BihT, BuhT, BohT, c3, h3, LOFF[3], LOFF[4], LOFF[5]);
  // L2 (65536, ratio 2)
  k_level<1><<<1024, 256, 0, stream>>>(sen, Ep, h3, c3,
      BfhT, BihT, BuhT, BohT, c2, h2, LOFF[2]);
  // L1 (16384, ratio 4)
  k_level<2><<<512, 256, 0, stream>>>(sen, Ep, h2, c2,
      BfhT, BihT, BuhT, BohT, c1, h1, LOFF[1]);
  // L0 (4096, ratio 4)
  k_level<2><<<128, 256, 0, stream>>>(sen, Ep, h1, c1,
      BfhT, BihT, BuhT, BohT, c0, h0, LOFF[0]);

  out_proj<<<64, 256, 0, stream>>>(h0, W_out, b_out, out);
}